// Round 26
// baseline (155.687 us; speedup 1.0000x reference)
//
#include <hip/hip_runtime.h>
#include <hip/hip_bf16.h>

#define D 128        // EMBED == LAYER == 128
#define BSHIFT 6     // 64 users per bucket
#define BUSERS (1 << BSHIFT)
#define NBLK 256     // scatter blocks
#define NSH 8        // reservation shards (chain length 256/8 = 32 RMWs)
#define CAPG 256     // per-(bucket,shard) capacity (mean 128, ~11 sigma)
#define CHUNK 1280   // edges staged per bucket-chunk (avg bucket ~1024)
#define MROWS 64     // pw: item rows per block

typedef __attribute__((ext_vector_type(8))) short bf16x8;
typedef __attribute__((ext_vector_type(4))) float f32x4;
typedef _Float16 f16x2 __attribute__((ext_vector_type(2)));

// round-to-nearest f32 -> bf16 bits
__device__ __forceinline__ unsigned int bf16rn(float f) {
  unsigned int u = __float_as_uint(f);
  return (u + 0x7fffu + ((u >> 16) & 1u)) >> 16;
}
// f32 -> fp16 bits (RNE via hardware cvt)
__device__ __forceinline__ unsigned short fp16rn(float f) {
  _Float16 h = (_Float16)f;
  return *reinterpret_cast<unsigned short*>(&h);
}

// ---------------------------------------------------------------------------
// pw tile body: P[m0:m0+64] = emb @ W, MFMA bf16, FP16 output (proven r20).
// ---------------------------------------------------------------------------
__device__ __forceinline__ void pw_tile(
    const float* __restrict__ emb, const float* __restrict__ W,
    unsigned short* __restrict__ Ph, int n_items, int tile,
    unsigned short* Wt /* 128*128 shorts, swizzled */) {
  const int tid = threadIdx.x;
  const int m0 = tile * MROWS;

  for (int i = tid; i < 128 * 128; i += 256) {
    const int k = i >> 7, c = i & 127;
    const unsigned short v = (unsigned short)bf16rn(W[i]);
    const int boff = c * 256 + ((2 * k) ^ ((c & 7) << 4));
    *reinterpret_cast<unsigned short*>(reinterpret_cast<char*>(Wt) + boff) = v;
  }

  const int w = tid >> 6;
  const int lane = tid & 63;
  const int lr = lane & 15;
  const int lg = lane >> 4;

  bf16x8 a[4];
  const int gr = m0 + w * 16 + lr;
#pragma unroll
  for (int ks = 0; ks < 4; ++ks) {
    float4 f0 = {0.f, 0.f, 0.f, 0.f}, f1 = {0.f, 0.f, 0.f, 0.f};
    if (gr < n_items) {
      const float* p = emb + (size_t)gr * 128 + ks * 32 + lg * 8;
      f0 = *reinterpret_cast<const float4*>(p);
      f1 = *reinterpret_cast<const float4*>(p + 4);
    }
    bf16x8 av;
    av[0] = (short)bf16rn(f0.x); av[1] = (short)bf16rn(f0.y);
    av[2] = (short)bf16rn(f0.z); av[3] = (short)bf16rn(f0.w);
    av[4] = (short)bf16rn(f1.x); av[5] = (short)bf16rn(f1.y);
    av[6] = (short)bf16rn(f1.z); av[7] = (short)bf16rn(f1.w);
    a[ks] = av;
  }
  __syncthreads();  // Wt ready

  f32x4 acc[8];
#pragma unroll
  for (int cs = 0; cs < 8; ++cs) acc[cs] = {0.f, 0.f, 0.f, 0.f};

#pragma unroll
  for (int cs = 0; cs < 8; ++cs) {
    const int c = cs * 16 + lr;
#pragma unroll
    for (int ks = 0; ks < 4; ++ks) {
      const int boff = c * 256 + (((ks * 64) + lg * 16) ^ ((lr & 7) << 4));
      const bf16x8 b = *reinterpret_cast<const bf16x8*>(
          reinterpret_cast<const char*>(Wt) + boff);
      acc[cs] = __builtin_amdgcn_mfma_f32_16x16x32_bf16(a[ks], b, acc[cs],
                                                        0, 0, 0);
    }
  }

#pragma unroll
  for (int cs = 0; cs < 8; ++cs) {
    const int c = cs * 16 + lr;
#pragma unroll
    for (int reg = 0; reg < 4; ++reg) {
      const int r = m0 + w * 16 + lg * 4 + reg;
      if (r < n_items)
        Ph[(size_t)r * 128 + c] = fp16rn(acc[cs][reg]);
    }
  }
}

// ---------------------------------------------------------------------------
// Kernel 1 (fused, INTERLEAVED roles): scatter role on blockIdx%4==0
// (idx/4 < NBLK); pw tiles on the rest. Scatter blocks are co-resident with
// pw for the whole dispatch -> their memory latency hides under pw compute;
// no 1-block/CU scatter tail (r25's 16% occupancy signature).
// ---------------------------------------------------------------------------
__global__ __launch_bounds__(256) void pw_scatter_kernel(
    const float* __restrict__ emb, const float* __restrict__ W,
    unsigned short* __restrict__ Ph, int n_items, int npw,
    const int* __restrict__ rows, const int* __restrict__ cols,
    const float* __restrict__ vals, int* __restrict__ gcur,
    int2* __restrict__ sedge, int n_edges, int epb, int nbuck) {
  __shared__ __align__(16) char smem[32768];
  const int tid = threadIdx.x;
  const int idx = (int)blockIdx.x;

  int sb = -1;
  if ((idx & 3) == 0 && (idx >> 2) < NBLK) sb = idx >> 2;

  if (sb < 0) {
    // pw tile index: idx minus #scatter blocks preceding it
    const int t = (idx < NBLK * 4) ? (idx - (idx >> 2) - 1) : (idx - NBLK);
    pw_tile(emb, W, Ph, n_items, t, (unsigned short*)smem);
    return;
  }
  int* hcnt = (int*)smem;          // nbuck counts
  int* lcur = hcnt + nbuck;        // nbuck cursors (2*1563*4 = 12.5 KB)
  const int g = sb & (NSH - 1);    // this block's shard
  for (int b = tid; b < nbuck; b += 256) hcnt[b] = 0;
  __syncthreads();
  const int e0 = sb * epb;
  const int e1 = (e0 + epb < n_edges) ? e0 + epb : n_edges;
  for (int e = e0 + tid; e < e1; e += 256)
    atomicAdd(&hcnt[rows[e] >> BSHIFT], 1);
  __syncthreads();
  for (int b = tid; b < nbuck; b += 256) {
    const int c = hcnt[b];
    lcur[b] = (c > 0) ? atomicAdd(&gcur[b * NSH + g], c) : 0;
  }
  __syncthreads();
  for (int e = e0 + tid; e < e1; e += 256) {
    const int r = rows[e];
    const int b = r >> BSHIFT;
    const int pos = atomicAdd(&lcur[b], 1);
    if (pos < CAPG)
      sedge[((size_t)b * NSH + g) * CAPG + pos] = make_int2(
          ((r & (BUSERS - 1)) << 16) | cols[e], __float_as_int(vals[e]));
  }
}

// ---------------------------------------------------------------------------
// Kernel 2: per-bucket 64-key LDS counting-sort + lockstep quarter-wave
// accumulation with packed fp16 FMA (r18 lockstep; r23-verified). Bucket
// edges live in NSH sub-segments, concatenated via an LDS prefix table.
// ---------------------------------------------------------------------------
__global__ __launch_bounds__(256) void bucket_gather_kernel(
    const uint4* __restrict__ Ph4,  // fp16, 16 uint4 per 256-B row
    const int* __restrict__ gcur, const int2* __restrict__ sedge,
    const float* __restrict__ nj, float* __restrict__ out, int n_users,
    int nbuck) {
  __shared__ int2 eraw[CHUNK];    // 10 KB
  __shared__ int2 esort[CHUNK];   // 10 KB
  __shared__ int cnt[BUSERS];
  __shared__ int incl[BUSERS];
  __shared__ int psum[NSH + 1];   // sub-segment concatenation offsets

  const int tid = threadIdx.x;
  const int b = blockIdx.x;
  const int u0 = b << BSHIFT;
  const int qw = tid >> 4;        // quarter-wave 0..15
  const int l16 = tid & 15;       // lane within quarter-wave

  if (tid == 0) {
    int s = 0;
    psum[0] = 0;
#pragma unroll
    for (int gg = 0; gg < NSH; ++gg) {
      int c = gcur[b * NSH + gg];
      if (c > CAPG) c = CAPG;
      s += c;
      psum[gg + 1] = s;
    }
  }
  __syncthreads();
  const int bc = psum[NSH];

  f16x2 acc[4][4];                // 4 users x 4 fp16-pairs (8 cols)
#pragma unroll
  for (int k = 0; k < 4; ++k)
#pragma unroll
    for (int m = 0; m < 4; ++m) acc[k][m] = (f16x2){(_Float16)0, (_Float16)0};

  for (int cbeg = 0; cbeg < bc; cbeg += CHUNK) {
    const int cnum = (cbeg + CHUNK < bc) ? CHUNK : (bc - cbeg);
    if (tid < BUSERS) cnt[tid] = 0;
    __syncthreads();
    for (int i = tid; i < cnum; i += 256) {
      const int cidx = cbeg + i;
      int g = 0;
#pragma unroll
      for (int gg = 1; gg < NSH; ++gg) g += (cidx >= psum[gg]);
      const int2 e =
          sedge[((size_t)b * NSH + g) * CAPG + (cidx - psum[g])];
      eraw[i] = e;
      atomicAdd(&cnt[((unsigned int)e.x) >> 16], 1);
    }
    __syncthreads();
    if (tid < BUSERS) incl[tid] = cnt[tid];
    __syncthreads();
    for (int s = 1; s < BUSERS; s <<= 1) {
      int y = 0;
      if (tid < BUSERS && tid >= s) y = incl[tid - s];
      __syncthreads();
      if (tid < BUSERS) incl[tid] += y;
      __syncthreads();
    }
    if (tid < BUSERS) cnt[tid] = incl[tid] - cnt[tid];
    __syncthreads();
    for (int i = tid; i < cnum; i += 256) {
      const int2 e = eraw[i];
      const int pos = atomicAdd(&cnt[((unsigned int)e.x) >> 16], 1);
      esort[pos] = e;
    }
    __syncthreads();

    // accumulate: lockstep groups, predicated edges, packed fp16 FMA
    if (cnum > 0) {
#pragma unroll
      for (int k = 0; k < 4; ++k) {
        const int ul = qw * 4 + k;
        const int s = (ul == 0) ? 0 : incl[ul - 1];
        const int t = incl[ul];
        // wave-uniform max segment length across this wave's 4 groups
        const int ub = ((qw >> 2) << 4) + k;   // wave*16 + k
        int wlen = 0;
#pragma unroll
        for (int m = 0; m < 4; ++m) {
          const int u2 = ub + m * 4;
          const int s2 = (u2 == 0) ? 0 : incl[u2 - 1];
          const int l2 = incl[u2] - s2;
          wlen = (l2 > wlen) ? l2 : wlen;
        }
        for (int i = 0; i < wlen; i += 8) {
          int2 e[8];
          uint4 p[8];
          _Float16 hv[8];
#pragma unroll
          for (int q = 0; q < 8; ++q) {
            const int j = s + i + q;
            const bool ok = (j < t);
            e[q] = esort[ok ? j : 0];
            hv[q] = (_Float16)(ok ? __int_as_float(e[q].y) : 0.f);
          }
#pragma unroll
          for (int q = 0; q < 8; ++q)
            p[q] = Ph4[(size_t)(e[q].x & 0xffff) * 16 + l16];
#pragma unroll
          for (int q = 0; q < 8; ++q) {
            const f16x2 vh = {hv[q], hv[q]};
            acc[k][0] = __builtin_elementwise_fma(
                vh, __builtin_bit_cast(f16x2, p[q].x), acc[k][0]);
            acc[k][1] = __builtin_elementwise_fma(
                vh, __builtin_bit_cast(f16x2, p[q].y), acc[k][1]);
            acc[k][2] = __builtin_elementwise_fma(
                vh, __builtin_bit_cast(f16x2, p[q].z), acc[k][2]);
            acc[k][3] = __builtin_elementwise_fma(
                vh, __builtin_bit_cast(f16x2, p[q].w), acc[k][3]);
          }
        }
      }
    }
    __syncthreads();  // protect LDS before next chunk
  }

  // epilogue: convert fp16 acc -> f32, scale by nj, two float4 stores
#pragma unroll
  for (int k = 0; k < 4; ++k) {
    const int u = u0 + qw * 4 + k;
    if (u < n_users) {
      const float s = nj[u];
      float4 a0, a1;
      a0.x = (float)acc[k][0][0] * s; a0.y = (float)acc[k][0][1] * s;
      a0.z = (float)acc[k][1][0] * s; a0.w = (float)acc[k][1][1] * s;
      a1.x = (float)acc[k][2][0] * s; a1.y = (float)acc[k][2][1] * s;
      a1.z = (float)acc[k][3][0] * s; a1.w = (float)acc[k][3][1] * s;
      float* o = out + (size_t)u * D + l16 * 8;
      *reinterpret_cast<float4*>(o) = a0;
      *reinterpret_cast<float4*>(o + 4) = a1;
    }
  }
}

extern "C" void kernel_launch(void* const* d_in, const int* in_sizes, int n_in,
                              void* d_out, int out_size, void* d_ws,
                              size_t ws_size, hipStream_t stream) {
  const float* item_emb = (const float*)d_in[0];  // [n_items, 128]
  const float* user_nj  = (const float*)d_in[1];  // [n_users, 1]
  const float* weight   = (const float*)d_in[2];  // [128, 128]
  const float* adj_vals = (const float*)d_in[3];  // [E]
  const int*   adj_rows = (const int*)d_in[4];    // [E]
  const int*   adj_cols = (const int*)d_in[5];    // [E]

  const int n_items = in_sizes[0] / D;
  const int n_users = in_sizes[1];
  const int n_edges = in_sizes[3];
  float* out = (float*)d_out;

  const int nbuck = (n_users + BUSERS - 1) >> BSHIFT;  // 1563
  const int npw = (n_items + MROWS - 1) / MROWS;       // 782
  const int epb = (n_edges + NBLK - 1) / NBLK;         // 6250

  // ---- workspace layout (256B-aligned) ----
  auto align256 = [](size_t x) { return (x + 255) & ~(size_t)255; };
  char* ws = (char*)d_ws;
  size_t off = 0;
  unsigned short* Ph = (unsigned short*)(ws + off);
  off = align256(off + (size_t)n_items * D * 2);          // 12.8 MB fp16
  int2* sedge = (int2*)(ws + off);
  off = align256(off + (size_t)nbuck * NSH * CAPG * 8);   // 25.6 MB
  int* gcur = (int*)(ws + off);
  off = align256(off + (size_t)nbuck * NSH * 4);          // 50 KB

  // 0) zero sharded bucket fill counters (graph-replay-safe)
  hipMemsetAsync(gcur, 0, (size_t)nbuck * NSH * 4, stream);

  // 1) fused: pw tiles || scatter-direct, roles INTERLEAVED by blockIdx
  pw_scatter_kernel<<<npw + NBLK, 256, 0, stream>>>(
      item_emb, weight, Ph, n_items, npw, adj_rows, adj_cols, adj_vals,
      gcur, sedge, n_edges, epb, nbuck);

  // 2) per-bucket counting-sort + lockstep fp16-packed register gather
  bucket_gather_kernel<<<nbuck, 256, 0, stream>>>(
      reinterpret_cast<const uint4*>(Ph), gcur, sedge, user_nj, out,
      n_users, nbuck);
}

// Round 28
// 124.991 us; speedup vs baseline: 1.2456x; 1.2456x over previous
//
#include <hip/hip_runtime.h>
#include <hip/hip_bf16.h>

#define D 128        // EMBED == LAYER == 128
#define BSHIFT 6     // 64 users per bucket
#define BUSERS (1 << BSHIFT)
#define NBLK 256     // blocks for hist/scatter passes
#define CHUNK 1280   // edges staged per bucket-chunk (avg bucket ~1024)
#define MROWS 64     // pw: item rows per block

typedef __attribute__((ext_vector_type(8))) short bf16x8;
typedef __attribute__((ext_vector_type(4))) float f32x4;
typedef _Float16 f16x2 __attribute__((ext_vector_type(2)));

// round-to-nearest f32 -> bf16 bits
__device__ __forceinline__ unsigned int bf16rn(float f) {
  unsigned int u = __float_as_uint(f);
  return (u + 0x7fffu + ((u >> 16) & 1u)) >> 16;
}
// f32 -> fp16 bits (RNE via hardware cvt)
__device__ __forceinline__ unsigned short fp16rn(float f) {
  _Float16 h = (_Float16)f;
  return *reinterpret_cast<unsigned short*>(&h);
}

// ---------------------------------------------------------------------------
// Kernel 0: one-time W (f32, [k][c]) -> Wbf (bf16, TRANSPOSED [c][k]).
// 32 KB result lives in every XCD's L2 for the pw tiles.
// ---------------------------------------------------------------------------
__global__ __launch_bounds__(256) void wconv_kernel(
    const float* __restrict__ W, unsigned short* __restrict__ Wbf) {
  const int i = blockIdx.x * 256 + threadIdx.x;  // i = k*128 + c
  if (i < 128 * 128) {
    const int k = i >> 7, c = i & 127;
    Wbf[c * 128 + k] = (unsigned short)bf16rn(W[i]);
  }
}

// ---------------------------------------------------------------------------
// pw tile body: P[m0:m0+64] = emb @ W, MFMA bf16, FP16 output.
// ZERO LDS: A-fragments direct from global emb; B-fragments direct from
// global Wbf (L2-resident 32 KB). No barrier, no staging.
// ---------------------------------------------------------------------------
__device__ __forceinline__ void pw_tile(
    const float* __restrict__ emb, const unsigned short* __restrict__ Wbf,
    unsigned short* __restrict__ Ph, int n_items, int tile) {
  const int tid = threadIdx.x;
  const int m0 = tile * MROWS;

  const int w = tid >> 6;
  const int lane = tid & 63;
  const int lr = lane & 15;
  const int lg = lane >> 4;

  // A fragments: row gr, k = ks*32 + lg*8 + j
  bf16x8 a[4];
  const int gr = m0 + w * 16 + lr;
#pragma unroll
  for (int ks = 0; ks < 4; ++ks) {
    float4 f0 = {0.f, 0.f, 0.f, 0.f}, f1 = {0.f, 0.f, 0.f, 0.f};
    if (gr < n_items) {
      const float* p = emb + (size_t)gr * 128 + ks * 32 + lg * 8;
      f0 = *reinterpret_cast<const float4*>(p);
      f1 = *reinterpret_cast<const float4*>(p + 4);
    }
    bf16x8 av;
    av[0] = (short)bf16rn(f0.x); av[1] = (short)bf16rn(f0.y);
    av[2] = (short)bf16rn(f0.z); av[3] = (short)bf16rn(f0.w);
    av[4] = (short)bf16rn(f1.x); av[5] = (short)bf16rn(f1.y);
    av[6] = (short)bf16rn(f1.z); av[7] = (short)bf16rn(f1.w);
    a[ks] = av;
  }

  f32x4 acc[8];
#pragma unroll
  for (int cs = 0; cs < 8; ++cs) acc[cs] = {0.f, 0.f, 0.f, 0.f};

#pragma unroll
  for (int cs = 0; cs < 8; ++cs) {
    const int c = cs * 16 + lr;
#pragma unroll
    for (int ks = 0; ks < 4; ++ks) {
      // B fragment: Wbf[c][ks*32 + lg*8 ..+7] — 16 B/lane from L2
      const bf16x8 b = *reinterpret_cast<const bf16x8*>(
          Wbf + (size_t)c * 128 + ks * 32 + lg * 8);
      acc[cs] = __builtin_amdgcn_mfma_f32_16x16x32_bf16(a[ks], b, acc[cs],
                                                        0, 0, 0);
    }
  }

#pragma unroll
  for (int cs = 0; cs < 8; ++cs) {
    const int c = cs * 16 + lr;
#pragma unroll
    for (int reg = 0; reg < 4; ++reg) {
      const int r = m0 + w * 16 + lg * 4 + reg;
      if (r < n_items)
        Ph[(size_t)r * 128 + c] = fp16rn(acc[cs][reg]);
    }
  }
}

// ---------------------------------------------------------------------------
// Kernel 1 (fused): blocks [0, npw1) -> pw tiles; [npw1, npw1+NBLK) -> hist.
// Only 6.4 KB LDS (hist role) -> high occupancy for pw.
// ---------------------------------------------------------------------------
__global__ __launch_bounds__(256) void pw_hist_kernel(
    const float* __restrict__ emb, const unsigned short* __restrict__ Wbf,
    unsigned short* __restrict__ Ph, int n_items, int npw1,
    const int* __restrict__ rows, int* __restrict__ bcount, int n_edges,
    int epb, int nbuck) {
  __shared__ int h[1600];
  const int tid = threadIdx.x;

  if ((int)blockIdx.x < npw1) {
    pw_tile(emb, Wbf, Ph, n_items, blockIdx.x);
  } else {
    const int hb = blockIdx.x - npw1;
    for (int b = tid; b < nbuck; b += 256) h[b] = 0;
    __syncthreads();
    const int e0 = hb * epb;
    const int e1 = (e0 + epb < n_edges) ? e0 + epb : n_edges;
    for (int e = e0 + tid; e < e1; e += 256)
      atomicAdd(&h[rows[e] >> BSHIFT], 1);
    __syncthreads();
    for (int b = tid; b < nbuck; b += 256)
      bcount[(size_t)b * NBLK + hb] = h[b];
  }
}

// ---------------------------------------------------------------------------
// 3-kernel exclusive scan over bcount (nbuck*NBLK entries) -> base.
// NO inter-block communication/fences (r12/r21 lessons).
// ---------------------------------------------------------------------------
__global__ __launch_bounds__(1024) void blocksum_kernel(
    const int* __restrict__ in, int* __restrict__ partials, int n) {
  __shared__ int lds[1024];
  const int tid = threadIdx.x;
  const int i = blockIdx.x * 1024 + tid;
  lds[tid] = (i < n) ? in[i] : 0;
  __syncthreads();
  for (int s = 512; s > 0; s >>= 1) {
    if (tid < s) lds[tid] += lds[tid + s];
    __syncthreads();
  }
  if (tid == 0) partials[blockIdx.x] = lds[0];
}

__global__ __launch_bounds__(1024) void scanpart_kernel(
    const int* __restrict__ partials, int* __restrict__ blockoff, int nb) {
  __shared__ int lds[1024];
  const int tid = threadIdx.x;
  const int x = (tid < nb) ? partials[tid] : 0;
  lds[tid] = x;
  __syncthreads();
  for (int s = 1; s < 1024; s <<= 1) {
    const int y = (tid >= s) ? lds[tid - s] : 0;
    __syncthreads();
    lds[tid] += y;
    __syncthreads();
  }
  if (tid < nb) blockoff[tid] = lds[tid] - x;
}

__global__ __launch_bounds__(1024) void localscan_kernel(
    const int* __restrict__ in, const int* __restrict__ blockoff,
    int* __restrict__ base, int n) {
  __shared__ int lds[1024];
  const int tid = threadIdx.x;
  const int i = blockIdx.x * 1024 + tid;
  const int x = (i < n) ? in[i] : 0;
  lds[tid] = x;
  __syncthreads();
  for (int s = 1; s < 1024; s <<= 1) {
    const int y = (tid >= s) ? lds[tid - s] : 0;
    __syncthreads();
    lds[tid] += y;
    __syncthreads();
  }
  if (i < n) base[i] = blockoff[blockIdx.x] + lds[tid] - x;
}

// ---------------------------------------------------------------------------
// Kernel 3 (fused): blocks [0, NBLK) -> scatter; [NBLK, NBLK+npw2) -> pw.
// ---------------------------------------------------------------------------
__global__ __launch_bounds__(256) void scatter_pw_kernel(
    const int* __restrict__ rows, const int* __restrict__ cols,
    const float* __restrict__ vals, const int* __restrict__ base,
    int2* __restrict__ sedge, int n_edges, int epb, int nbuck,
    const float* __restrict__ emb, const unsigned short* __restrict__ Wbf,
    unsigned short* __restrict__ Ph, int n_items, int npw1) {
  __shared__ int cur[1600];
  const int tid = threadIdx.x;

  if ((int)blockIdx.x >= NBLK) {
    pw_tile(emb, Wbf, Ph, n_items, npw1 + (int)blockIdx.x - NBLK);
    return;
  }
  for (int b = tid; b < nbuck; b += 256)
    cur[b] = base[(size_t)b * NBLK + blockIdx.x];
  __syncthreads();
  const int e0 = blockIdx.x * epb;
  const int e1 = (e0 + epb < n_edges) ? e0 + epb : n_edges;
  for (int e = e0 + tid; e < e1; e += 256) {
    const int r = rows[e];
    const int pos = atomicAdd(&cur[r >> BSHIFT], 1);
    sedge[pos] =
        make_int2(((r & (BUSERS - 1)) << 16) | cols[e], __float_as_int(vals[e]));
  }
}

// ---------------------------------------------------------------------------
// Kernel 4: per-bucket 64-key LDS counting-sort + lockstep quarter-wave
// accumulation with packed fp16 FMA (r18 lockstep, r23-verified).
// ---------------------------------------------------------------------------
__global__ __launch_bounds__(256) void bucket_gather_kernel(
    const uint4* __restrict__ Ph4,  // fp16, 16 uint4 per 256-B row
    const int* __restrict__ base, const int2* __restrict__ sedge,
    const float* __restrict__ nj, float* __restrict__ out, int n_users,
    int n_edges, int nbuck) {
  __shared__ int2 eraw[CHUNK];    // 10 KB
  __shared__ int2 esort[CHUNK];   // 10 KB
  __shared__ int cnt[BUSERS];
  __shared__ int incl[BUSERS];

  const int tid = threadIdx.x;
  const int b = blockIdx.x;
  const int u0 = b << BSHIFT;
  const int qw = tid >> 4;        // quarter-wave 0..15
  const int l16 = tid & 15;       // lane within quarter-wave

  const int beg = base[(size_t)b * NBLK];
  const int end = (b + 1 < nbuck) ? base[(size_t)(b + 1) * NBLK] : n_edges;

  f16x2 acc[4][4];                // 4 users x 4 fp16-pairs (8 cols)
#pragma unroll
  for (int k = 0; k < 4; ++k)
#pragma unroll
    for (int m = 0; m < 4; ++m) acc[k][m] = (f16x2){(_Float16)0, (_Float16)0};

  for (int cbeg = beg; cbeg < end; cbeg += CHUNK) {
    const int cnum = (cbeg + CHUNK < end) ? CHUNK : (end - cbeg);
    if (tid < BUSERS) cnt[tid] = 0;
    __syncthreads();
    for (int i = tid; i < cnum; i += 256) {
      const int2 e = sedge[cbeg + i];
      eraw[i] = e;
      atomicAdd(&cnt[((unsigned int)e.x) >> 16], 1);
    }
    __syncthreads();
    if (tid < BUSERS) incl[tid] = cnt[tid];
    __syncthreads();
    for (int s = 1; s < BUSERS; s <<= 1) {
      int y = 0;
      if (tid < BUSERS && tid >= s) y = incl[tid - s];
      __syncthreads();
      if (tid < BUSERS) incl[tid] += y;
      __syncthreads();
    }
    if (tid < BUSERS) cnt[tid] = incl[tid] - cnt[tid];
    __syncthreads();
    for (int i = tid; i < cnum; i += 256) {
      const int2 e = eraw[i];
      const int pos = atomicAdd(&cnt[((unsigned int)e.x) >> 16], 1);
      esort[pos] = e;
    }
    __syncthreads();

    // accumulate: lockstep groups, predicated edges, packed fp16 FMA
    if (cnum > 0) {
#pragma unroll
      for (int k = 0; k < 4; ++k) {
        const int ul = qw * 4 + k;
        const int s = (ul == 0) ? 0 : incl[ul - 1];
        const int t = incl[ul];
        // wave-uniform max segment length across this wave's 4 groups
        const int ub = ((qw >> 2) << 4) + k;   // wave*16 + k
        int wlen = 0;
#pragma unroll
        for (int m = 0; m < 4; ++m) {
          const int u2 = ub + m * 4;
          const int s2 = (u2 == 0) ? 0 : incl[u2 - 1];
          const int l2 = incl[u2] - s2;
          wlen = (l2 > wlen) ? l2 : wlen;
        }
        for (int i = 0; i < wlen; i += 8) {
          int2 e[8];
          uint4 p[8];
          _Float16 hv[8];
#pragma unroll
          for (int q = 0; q < 8; ++q) {
            const int j = s + i + q;
            const bool ok = (j < t);
            e[q] = esort[ok ? j : 0];
            hv[q] = (_Float16)(ok ? __int_as_float(e[q].y) : 0.f);
          }
#pragma unroll
          for (int q = 0; q < 8; ++q)
            p[q] = Ph4[(size_t)(e[q].x & 0xffff) * 16 + l16];
#pragma unroll
          for (int q = 0; q < 8; ++q) {
            const f16x2 vh = {hv[q], hv[q]};
            acc[k][0] = __builtin_elementwise_fma(
                vh, __builtin_bit_cast(f16x2, p[q].x), acc[k][0]);
            acc[k][1] = __builtin_elementwise_fma(
                vh, __builtin_bit_cast(f16x2, p[q].y), acc[k][1]);
            acc[k][2] = __builtin_elementwise_fma(
                vh, __builtin_bit_cast(f16x2, p[q].z), acc[k][2]);
            acc[k][3] = __builtin_elementwise_fma(
                vh, __builtin_bit_cast(f16x2, p[q].w), acc[k][3]);
          }
        }
      }
    }
    __syncthreads();  // protect LDS before next chunk
  }

  // epilogue: convert fp16 acc -> f32, scale by nj, two float4 stores
#pragma unroll
  for (int k = 0; k < 4; ++k) {
    const int u = u0 + qw * 4 + k;
    if (u < n_users) {
      const float s = nj[u];
      float4 a0, a1;
      a0.x = (float)acc[k][0][0] * s; a0.y = (float)acc[k][0][1] * s;
      a0.z = (float)acc[k][1][0] * s; a0.w = (float)acc[k][1][1] * s;
      a1.x = (float)acc[k][2][0] * s; a1.y = (float)acc[k][2][1] * s;
      a1.z = (float)acc[k][3][0] * s; a1.w = (float)acc[k][3][1] * s;
      float* o = out + (size_t)u * D + l16 * 8;
      *reinterpret_cast<float4*>(o) = a0;
      *reinterpret_cast<float4*>(o + 4) = a1;
    }
  }
}

extern "C" void kernel_launch(void* const* d_in, const int* in_sizes, int n_in,
                              void* d_out, int out_size, void* d_ws,
                              size_t ws_size, hipStream_t stream) {
  const float* item_emb = (const float*)d_in[0];  // [n_items, 128]
  const float* user_nj  = (const float*)d_in[1];  // [n_users, 1]
  const float* weight   = (const float*)d_in[2];  // [128, 128]
  const float* adj_vals = (const float*)d_in[3];  // [E]
  const int*   adj_rows = (const int*)d_in[4];    // [E]
  const int*   adj_cols = (const int*)d_in[5];    // [E]

  const int n_items = in_sizes[0] / D;
  const int n_users = in_sizes[1];
  const int n_edges = in_sizes[3];
  float* out = (float*)d_out;

  const int nbuck = (n_users + BUSERS - 1) >> BSHIFT;  // 1563
  const int npw = (n_items + MROWS - 1) / MROWS;       // 782
  const int npw1 = (npw + 1) / 2;                      // 391 (stage 1)
  const int npw2 = npw - npw1;                         // 391 (stage 3)
  const int epb = (n_edges + NBLK - 1) / NBLK;         // 6250
  const int n_scan = nbuck * NBLK;                     // 400128
  const int nb_scan = (n_scan + 1023) / 1024;          // 391

  // ---- workspace layout (256B-aligned) ----
  auto align256 = [](size_t x) { return (x + 255) & ~(size_t)255; };
  char* ws = (char*)d_ws;
  size_t off = 0;
  unsigned short* Ph = (unsigned short*)(ws + off);
  off = align256(off + (size_t)n_items * D * 2);  // 12.8 MB fp16
  int* bcount = (int*)(ws + off);  off = align256(off + (size_t)n_scan * 4);
  int* base = (int*)(ws + off);    off = align256(off + (size_t)n_scan * 4);
  int2* sedge = (int2*)(ws + off); off = align256(off + (size_t)n_edges * 8);
  int* partials = (int*)(ws + off); off = align256(off + (size_t)nb_scan * 4);
  int* blockoff = (int*)(ws + off); off = align256(off + (size_t)nb_scan * 4);
  unsigned short* Wbf = (unsigned short*)(ws + off);
  off = align256(off + 128 * 128 * 2);  // 32 KB

  // 0) one-time W -> transposed bf16 Wbf
  wconv_kernel<<<64, 256, 0, stream>>>(weight, Wbf);

  // 1) fused: pw tiles [0,npw1) || bucket histograms
  pw_hist_kernel<<<npw1 + NBLK, 256, 0, stream>>>(
      item_emb, Wbf, Ph, n_items, npw1, adj_rows, bcount, n_edges, epb,
      nbuck);

  // 2) 3-kernel exclusive scan of bcount -> base (no inter-block comms)
  blocksum_kernel<<<nb_scan, 1024, 0, stream>>>(bcount, partials, n_scan);
  scanpart_kernel<<<1, 1024, 0, stream>>>(partials, blockoff, nb_scan);
  localscan_kernel<<<nb_scan, 1024, 0, stream>>>(bcount, blockoff, base,
                                                 n_scan);

  // 3) fused: scatter pass || pw tiles [npw1, npw)
  scatter_pw_kernel<<<NBLK + npw2, 256, 0, stream>>>(
      adj_rows, adj_cols, adj_vals, base, sedge, n_edges, epb, nbuck,
      item_emb, Wbf, Ph, n_items, npw1);

  // 4) per-bucket counting-sort + lockstep fp16-packed register gather
  bucket_gather_kernel<<<nbuck, 256, 0, stream>>>(
      reinterpret_cast<const uint4*>(Ph), base, sedge, user_nj, out,
      n_users, n_edges, nbuck);
}

// Round 29
// 112.831 us; speedup vs baseline: 1.3798x; 1.1078x over previous
//
#include <hip/hip_runtime.h>
#include <hip/hip_bf16.h>

#define D 128        // EMBED == LAYER == 128
#define BSHIFT 6     // 64 users per bucket
#define BUSERS (1 << BSHIFT)
#define NBLK 256     // blocks for hist/scatter passes
#define CHUNK 1280   // edges staged per bucket-chunk (avg bucket ~1024)
#define MROWS 64     // pw: item rows per block

typedef __attribute__((ext_vector_type(8))) short bf16x8;
typedef __attribute__((ext_vector_type(4))) float f32x4;

// round-to-nearest f32 -> bf16 bits
__device__ __forceinline__ unsigned int bf16rn(float f) {
  unsigned int u = __float_as_uint(f);
  return (u + 0x7fffu + ((u >> 16) & 1u)) >> 16;
}

// ---------------------------------------------------------------------------
// pw tile body (device fn): P[m0:m0+64] = emb @ W, MFMA bf16.
// Wt (32 KB LDS) staged cooperatively; A-fragments loaded DIRECT from global
// (f32->bf16 in-register) — no A staging. (r28: zero-LDS variant with
// per-MFMA L2 B-reads was SLOWER; keep the one-time LDS stage.)
// ---------------------------------------------------------------------------
__device__ __forceinline__ void pw_tile(
    const float* __restrict__ emb, const float* __restrict__ W,
    unsigned short* __restrict__ Pb, int n_items, int tile,
    unsigned short* Wt /* 128*128 shorts, swizzled */) {
  const int tid = threadIdx.x;
  const int m0 = tile * MROWS;

  // stage W^T bf16 swizzled: Wt[c][k], boff = c*256 + ((2k)^((c&7)<<4))
  for (int i = tid; i < 128 * 128; i += 256) {
    const int k = i >> 7, c = i & 127;
    const unsigned short v = (unsigned short)bf16rn(W[i]);
    const int boff = c * 256 + ((2 * k) ^ ((c & 7) << 4));
    *reinterpret_cast<unsigned short*>(reinterpret_cast<char*>(Wt) + boff) = v;
  }

  const int w = tid >> 6;
  const int lane = tid & 63;
  const int lr = lane & 15;
  const int lg = lane >> 4;

  // A fragments direct from global: row gr, k = ks*32 + lg*8 + j
  bf16x8 a[4];
  const int gr = m0 + w * 16 + lr;
#pragma unroll
  for (int ks = 0; ks < 4; ++ks) {
    float4 f0 = {0.f, 0.f, 0.f, 0.f}, f1 = {0.f, 0.f, 0.f, 0.f};
    if (gr < n_items) {
      const float* p = emb + (size_t)gr * 128 + ks * 32 + lg * 8;
      f0 = *reinterpret_cast<const float4*>(p);
      f1 = *reinterpret_cast<const float4*>(p + 4);
    }
    bf16x8 av;
    av[0] = (short)bf16rn(f0.x); av[1] = (short)bf16rn(f0.y);
    av[2] = (short)bf16rn(f0.z); av[3] = (short)bf16rn(f0.w);
    av[4] = (short)bf16rn(f1.x); av[5] = (short)bf16rn(f1.y);
    av[6] = (short)bf16rn(f1.z); av[7] = (short)bf16rn(f1.w);
    a[ks] = av;
  }
  __syncthreads();  // Wt ready

  f32x4 acc[8];
#pragma unroll
  for (int cs = 0; cs < 8; ++cs) acc[cs] = {0.f, 0.f, 0.f, 0.f};

#pragma unroll
  for (int cs = 0; cs < 8; ++cs) {
    const int c = cs * 16 + lr;
#pragma unroll
    for (int ks = 0; ks < 4; ++ks) {
      const int boff = c * 256 + (((ks * 64) + lg * 16) ^ ((lr & 7) << 4));
      const bf16x8 b = *reinterpret_cast<const bf16x8*>(
          reinterpret_cast<const char*>(Wt) + boff);
      acc[cs] = __builtin_amdgcn_mfma_f32_16x16x32_bf16(a[ks], b, acc[cs],
                                                        0, 0, 0);
    }
  }

#pragma unroll
  for (int cs = 0; cs < 8; ++cs) {
    const int c = cs * 16 + lr;
#pragma unroll
    for (int reg = 0; reg < 4; ++reg) {
      const int r = m0 + w * 16 + lg * 4 + reg;
      if (r < n_items)
        Pb[(size_t)r * 128 + c] = (unsigned short)bf16rn(acc[cs][reg]);
    }
  }
}

// ---------------------------------------------------------------------------
// Kernel 1 (fused): blocks [0, npw1) -> pw tiles; [npw1, npw1+NBLK) -> hist.
// ---------------------------------------------------------------------------
__global__ __launch_bounds__(256) void pw_hist_kernel(
    const float* __restrict__ emb, const float* __restrict__ W,
    unsigned short* __restrict__ Pb, int n_items, int npw1,
    const int* __restrict__ rows, int* __restrict__ bcount, int n_edges,
    int epb, int nbuck) {
  __shared__ __align__(16) char smem[32768];
  const int tid = threadIdx.x;

  if ((int)blockIdx.x < npw1) {
    pw_tile(emb, W, Pb, n_items, blockIdx.x, (unsigned short*)smem);
  } else {
    int* h = (int*)smem;
    const int hb = blockIdx.x - npw1;
    for (int b = tid; b < nbuck; b += 256) h[b] = 0;
    __syncthreads();
    const int e0 = hb * epb;
    const int e1 = (e0 + epb < n_edges) ? e0 + epb : n_edges;
    for (int e = e0 + tid; e < e1; e += 256)
      atomicAdd(&h[rows[e] >> BSHIFT], 1);
    __syncthreads();
    for (int b = tid; b < nbuck; b += 256)
      bcount[(size_t)b * NBLK + hb] = h[b];
  }
}

// ---------------------------------------------------------------------------
// 3-kernel exclusive scan over bcount (nbuck*NBLK entries) -> base.
// NO inter-block communication/fences (r12/r21 lessons).
// ---------------------------------------------------------------------------
__global__ __launch_bounds__(1024) void blocksum_kernel(
    const int* __restrict__ in, int* __restrict__ partials, int n) {
  __shared__ int lds[1024];
  const int tid = threadIdx.x;
  const int i = blockIdx.x * 1024 + tid;
  lds[tid] = (i < n) ? in[i] : 0;
  __syncthreads();
  for (int s = 512; s > 0; s >>= 1) {
    if (tid < s) lds[tid] += lds[tid + s];
    __syncthreads();
  }
  if (tid == 0) partials[blockIdx.x] = lds[0];
}

__global__ __launch_bounds__(1024) void scanpart_kernel(
    const int* __restrict__ partials, int* __restrict__ blockoff, int nb) {
  __shared__ int lds[1024];
  const int tid = threadIdx.x;
  const int x = (tid < nb) ? partials[tid] : 0;
  lds[tid] = x;
  __syncthreads();
  for (int s = 1; s < 1024; s <<= 1) {
    const int y = (tid >= s) ? lds[tid - s] : 0;
    __syncthreads();
    lds[tid] += y;
    __syncthreads();
  }
  if (tid < nb) blockoff[tid] = lds[tid] - x;
}

__global__ __launch_bounds__(1024) void localscan_kernel(
    const int* __restrict__ in, const int* __restrict__ blockoff,
    int* __restrict__ base, int n) {
  __shared__ int lds[1024];
  const int tid = threadIdx.x;
  const int i = blockIdx.x * 1024 + tid;
  const int x = (i < n) ? in[i] : 0;
  lds[tid] = x;
  __syncthreads();
  for (int s = 1; s < 1024; s <<= 1) {
    const int y = (tid >= s) ? lds[tid - s] : 0;
    __syncthreads();
    lds[tid] += y;
    __syncthreads();
  }
  if (i < n) base[i] = blockoff[blockIdx.x] + lds[tid] - x;
}

// ---------------------------------------------------------------------------
// Kernel 3 (fused): blocks [0, NBLK) -> scatter; [NBLK, NBLK+npw2) -> pw.
// ---------------------------------------------------------------------------
__global__ __launch_bounds__(256) void scatter_pw_kernel(
    const int* __restrict__ rows, const int* __restrict__ cols,
    const float* __restrict__ vals, const int* __restrict__ base,
    int2* __restrict__ sedge, int n_edges, int epb, int nbuck,
    const float* __restrict__ emb, const float* __restrict__ W,
    unsigned short* __restrict__ Pb, int n_items, int npw1) {
  __shared__ __align__(16) char smem[32768];
  const int tid = threadIdx.x;

  if ((int)blockIdx.x >= NBLK) {
    pw_tile(emb, W, Pb, n_items, npw1 + (int)blockIdx.x - NBLK,
            (unsigned short*)smem);
    return;
  }
  int* cur = (int*)smem;
  for (int b = tid; b < nbuck; b += 256)
    cur[b] = base[(size_t)b * NBLK + blockIdx.x];
  __syncthreads();
  const int e0 = blockIdx.x * epb;
  const int e1 = (e0 + epb < n_edges) ? e0 + epb : n_edges;
  for (int e = e0 + tid; e < e1; e += 256) {
    const int r = rows[e];
    const int pos = atomicAdd(&cur[r >> BSHIFT], 1);
    sedge[pos] =
        make_int2(((r & (BUSERS - 1)) << 16) | cols[e], __float_as_int(vals[e]));
  }
}

// ---------------------------------------------------------------------------
// Kernel 4: per-bucket 64-key LDS counting-sort + lockstep quarter-wave
// register accumulation (r18: wave-uniform bounds keep 32 loads in flight).
// ---------------------------------------------------------------------------
__global__ __launch_bounds__(256) void bucket_gather_kernel(
    const uint4* __restrict__ Pb4,  // bf16, 16 uint4 per 256-B row
    const int* __restrict__ base, const int2* __restrict__ sedge,
    const float* __restrict__ nj, float* __restrict__ out, int n_users,
    int n_edges, int nbuck) {
  __shared__ int2 eraw[CHUNK];    // 10 KB
  __shared__ int2 esort[CHUNK];   // 10 KB
  __shared__ int cnt[BUSERS];
  __shared__ int incl[BUSERS];

  const int tid = threadIdx.x;
  const int b = blockIdx.x;
  const int u0 = b << BSHIFT;
  const int qw = tid >> 4;        // quarter-wave 0..15
  const int l16 = tid & 15;       // lane within quarter-wave

  const int beg = base[(size_t)b * NBLK];
  const int end = (b + 1 < nbuck) ? base[(size_t)(b + 1) * NBLK] : n_edges;

  float4 acc0[4], acc1[4];        // 4 users x 8 cols
#pragma unroll
  for (int k = 0; k < 4; ++k) {
    acc0[k] = {0.f, 0.f, 0.f, 0.f};
    acc1[k] = {0.f, 0.f, 0.f, 0.f};
  }

  for (int cbeg = beg; cbeg < end; cbeg += CHUNK) {
    const int cnum = (cbeg + CHUNK < end) ? CHUNK : (end - cbeg);
    if (tid < BUSERS) cnt[tid] = 0;
    __syncthreads();
    for (int i = tid; i < cnum; i += 256) {
      const int2 e = sedge[cbeg + i];
      eraw[i] = e;
      atomicAdd(&cnt[((unsigned int)e.x) >> 16], 1);
    }
    __syncthreads();
    if (tid < BUSERS) incl[tid] = cnt[tid];
    __syncthreads();
    for (int s = 1; s < BUSERS; s <<= 1) {
      int y = 0;
      if (tid < BUSERS && tid >= s) y = incl[tid - s];
      __syncthreads();
      if (tid < BUSERS) incl[tid] += y;
      __syncthreads();
    }
    if (tid < BUSERS) cnt[tid] = incl[tid] - cnt[tid];
    __syncthreads();
    for (int i = tid; i < cnum; i += 256) {
      const int2 e = eraw[i];
      const int pos = atomicAdd(&cnt[((unsigned int)e.x) >> 16], 1);
      esort[pos] = e;
    }
    __syncthreads();

    // register accumulate: lockstep groups, predicated edges
    if (cnum > 0) {
#pragma unroll
      for (int k = 0; k < 4; ++k) {
        const int ul = qw * 4 + k;
        const int s = (ul == 0) ? 0 : incl[ul - 1];
        const int t = incl[ul];
        // wave-uniform max segment length across this wave's 4 groups
        const int ub = ((qw >> 2) << 4) + k;   // wave*16 + k
        int wlen = 0;
#pragma unroll
        for (int m = 0; m < 4; ++m) {
          const int u2 = ub + m * 4;
          const int s2 = (u2 == 0) ? 0 : incl[u2 - 1];
          const int l2 = incl[u2] - s2;
          wlen = (l2 > wlen) ? l2 : wlen;
        }
        for (int i = 0; i < wlen; i += 8) {
          int2 e[8];
          uint4 p[8];
          float vv[8];
#pragma unroll
          for (int q = 0; q < 8; ++q) {
            const int j = s + i + q;
            const bool ok = (j < t);
            e[q] = esort[ok ? j : 0];
            vv[q] = ok ? __int_as_float(e[q].y) : 0.f;
          }
#pragma unroll
          for (int q = 0; q < 8; ++q)
            p[q] = Pb4[(size_t)(e[q].x & 0xffff) * 16 + l16];
#pragma unroll
          for (int q = 0; q < 8; ++q) {
            const float v = vv[q];
            acc0[k].x += v * __uint_as_float(p[q].x << 16);
            acc0[k].y += v * __uint_as_float(p[q].x & 0xffff0000u);
            acc0[k].z += v * __uint_as_float(p[q].y << 16);
            acc0[k].w += v * __uint_as_float(p[q].y & 0xffff0000u);
            acc1[k].x += v * __uint_as_float(p[q].z << 16);
            acc1[k].y += v * __uint_as_float(p[q].z & 0xffff0000u);
            acc1[k].z += v * __uint_as_float(p[q].w << 16);
            acc1[k].w += v * __uint_as_float(p[q].w & 0xffff0000u);
          }
        }
      }
    }
    __syncthreads();  // protect LDS before next chunk
  }

  // epilogue: scale by nj, two coalesced float4 stores per lane
#pragma unroll
  for (int k = 0; k < 4; ++k) {
    const int u = u0 + qw * 4 + k;
    if (u < n_users) {
      const float s = nj[u];
      float4 a0 = acc0[k], a1 = acc1[k];
      a0.x *= s; a0.y *= s; a0.z *= s; a0.w *= s;
      a1.x *= s; a1.y *= s; a1.z *= s; a1.w *= s;
      float* o = out + (size_t)u * D + l16 * 8;
      *reinterpret_cast<float4*>(o) = a0;
      *reinterpret_cast<float4*>(o + 4) = a1;
    }
  }
}

extern "C" void kernel_launch(void* const* d_in, const int* in_sizes, int n_in,
                              void* d_out, int out_size, void* d_ws,
                              size_t ws_size, hipStream_t stream) {
  const float* item_emb = (const float*)d_in[0];  // [n_items, 128]
  const float* user_nj  = (const float*)d_in[1];  // [n_users, 1]
  const float* weight   = (const float*)d_in[2];  // [128, 128]
  const float* adj_vals = (const float*)d_in[3];  // [E]
  const int*   adj_rows = (const int*)d_in[4];    // [E]
  const int*   adj_cols = (const int*)d_in[5];    // [E]

  const int n_items = in_sizes[0] / D;
  const int n_users = in_sizes[1];
  const int n_edges = in_sizes[3];
  float* out = (float*)d_out;

  const int nbuck = (n_users + BUSERS - 1) >> BSHIFT;  // 1563
  const int npw = (n_items + MROWS - 1) / MROWS;       // 782
  const int npw1 = (npw + 1) / 2;                      // 391 (stage 1)
  const int npw2 = npw - npw1;                         // 391 (stage 3)
  const int epb = (n_edges + NBLK - 1) / NBLK;         // 6250
  const int n_scan = nbuck * NBLK;                     // 400128
  const int nb_scan = (n_scan + 1023) / 1024;          // 391

  // ---- workspace layout (256B-aligned) ----
  auto align256 = [](size_t x) { return (x + 255) & ~(size_t)255; };
  char* ws = (char*)d_ws;
  size_t off = 0;
  unsigned short* Pb = (unsigned short*)(ws + off);
  off = align256(off + (size_t)n_items * D * 2);  // 12.8 MB bf16
  int* bcount = (int*)(ws + off);  off = align256(off + (size_t)n_scan * 4);
  int* base = (int*)(ws + off);    off = align256(off + (size_t)n_scan * 4);
  int2* sedge = (int2*)(ws + off); off = align256(off + (size_t)n_edges * 8);
  int* partials = (int*)(ws + off); off = align256(off + (size_t)nb_scan * 4);
  int* blockoff = (int*)(ws + off); off = align256(off + (size_t)nb_scan * 4);

  // 1) fused: pw tiles [0,npw1) || bucket histograms
  pw_hist_kernel<<<npw1 + NBLK, 256, 0, stream>>>(
      item_emb, weight, Pb, n_items, npw1, adj_rows, bcount, n_edges, epb,
      nbuck);

  // 2) 3-kernel exclusive scan of bcount -> base (no inter-block comms)
  blocksum_kernel<<<nb_scan, 1024, 0, stream>>>(bcount, partials, n_scan);
  scanpart_kernel<<<1, 1024, 0, stream>>>(partials, blockoff, nb_scan);
  localscan_kernel<<<nb_scan, 1024, 0, stream>>>(bcount, blockoff, base,
                                                 n_scan);

  // 3) fused: scatter pass || pw tiles [npw1, npw)
  scatter_pw_kernel<<<NBLK + npw2, 256, 0, stream>>>(
      adj_rows, adj_cols, adj_vals, base, sedge, n_edges, epb, nbuck,
      item_emb, weight, Pb, n_items, npw1);

  // 4) per-bucket counting-sort + lockstep quarter-wave register gather
  bucket_gather_kernel<<<nbuck, 256, 0, stream>>>(
      reinterpret_cast<const uint4*>(Pb), base, sedge, user_nj, out,
      n_users, n_edges, nbuck);
}